// Round 5
// baseline (56.570 us; speedup 1.0000x reference)
//
#include <hip/hip_runtime.h>
#include <hip/hip_bf16.h>

// out[b][d][n] = E[n][d], b<32, d<128, n<16384.
// R1 read path (coalesced f4 loads + LDS transpose) + R4 write path (long
// contiguous wave stores). Tile = 8d x 1024n, 8 batches/block:
//   - per (b,d) row: 4 KB contiguous run, 4 fully-contiguous 1 KB wave stores
//   - LDS row hoisted to regs once, stored to 8 batches (LDS reads / 8)
// Floor: 268 MB stores at ~7 TB/s ≈ 38 µs.

#define NN 16384
#define DD 128
#define NB 32
#define DT 8      // d per tile
#define NT 1024   // n per tile
#define BT 8      // batches per block

typedef float f4_t __attribute__((ext_vector_type(4)));

__global__ __launch_bounds__(256) void tree_embed_kernel(
    const float* __restrict__ E, float* __restrict__ out) {
    __shared__ float lds[DT][NT + 1];  // 8 x 1025 x 4 B = 32.8 KB -> 4 blk/CU

    const int d0 = blockIdx.x * DT;
    const int n0 = blockIdx.y * NT;
    const int b0 = blockIdx.z * BT;
    const int tid = threadIdx.x;

    // ---- Load E[n0:n0+1024][d0:d0+8], f4-coalesced (32 B per row-segment),
    //      transpose into LDS. 2-way bank aliasing on writes = free.
    {
        const int c = tid & 1;       // f4 within row: d_local = 4c..4c+3
        const int nl0 = tid >> 1;    // 0..127
        #pragma unroll
        for (int i = 0; i < NT / 128; ++i) {  // 8 iters
            const int n = nl0 + (i << 7);
            const f4_t v = *reinterpret_cast<const f4_t*>(
                &E[(size_t)(n0 + n) * DD + d0 + (c << 2)]);
            lds[(c << 2) + 0][n] = v.x;
            lds[(c << 2) + 1][n] = v.y;
            lds[(c << 2) + 2][n] = v.z;
            lds[(c << 2) + 3][n] = v.w;
        }
    }
    __syncthreads();

    // ---- Store: each wave owns rows d = w, w+4 (DT=8). Per row: hoist
    //      1024 floats/wave-slice to regs (4 f4/lane), write 8 batches,
    //      each as 4 contiguous 1 KB wave stores (4 KB run per (b,d)).
    const int l = tid & 63;
    const int w = tid >> 6;          // 0..3
    const size_t BSTRIDE = (size_t)DD * NN;
    #pragma unroll
    for (int r = 0; r < DT / 4; ++r) {        // 2 rows per wave
        const int d = (r << 2) + w;
        const int nb = l << 2;                // f4 base within row
        const f4_t v0 = *reinterpret_cast<const f4_t*>(&lds[d][nb]);
        const f4_t v1 = *reinterpret_cast<const f4_t*>(&lds[d][nb + 256]);
        const f4_t v2 = *reinterpret_cast<const f4_t*>(&lds[d][nb + 512]);
        const f4_t v3 = *reinterpret_cast<const f4_t*>(&lds[d][nb + 768]);
        float* obase = out + (size_t)(d0 + d) * NN + n0 + nb;
        #pragma unroll
        for (int b = 0; b < BT; ++b) {
            float* p = obase + (size_t)(b0 + b) * BSTRIDE;
            *reinterpret_cast<f4_t*>(p)       = v0;
            *reinterpret_cast<f4_t*>(p + 256) = v1;
            *reinterpret_cast<f4_t*>(p + 512) = v2;
            *reinterpret_cast<f4_t*>(p + 768) = v3;
        }
    }
}

extern "C" void kernel_launch(void* const* d_in, const int* in_sizes, int n_in,
                              void* d_out, int out_size, void* d_ws, size_t ws_size,
                              hipStream_t stream) {
    const float* E = (const float*)d_in[0];  // [16384,128]
    float* out = (float*)d_out;              // [32,128,16384,1]
    dim3 grid(DD / DT, NN / NT, NB / BT);    // 16 x 16 x 4 = 1024 blocks
    hipLaunchKernelGGL(tree_embed_kernel, grid, dim3(256), 0, stream, E, out);
}

// Round 6
// 46.153 us; speedup vs baseline: 1.2257x; 1.2257x over previous
//
#include <hip/hip_runtime.h>
#include <hip/hip_bf16.h>

// out[b][d][n] = E[n][d], b<32, d<128, n<16384.
// R1's winning store shape (d-fastest, 4x256B scattered segments per wave
// store instr) but BT=32: each block owns one 64-n tile and broadcasts it to
// ALL batches. E read exactly once (8 MB HBM total), grid = 256 long-lived
// blocks (1/CU), one barrier per block. 99% of runtime = pure store loop.
// Floor: 268 MB stores at ~7 TB/s ~= 38 us.

#define NN 16384
#define DD 128
#define NB 32
#define NT 64

typedef float f4_t __attribute__((ext_vector_type(4)));

__global__ __launch_bounds__(256) void tree_embed_kernel(
    const float* __restrict__ E, float* __restrict__ out) {
    __shared__ float lds[DD][NT + 1];  // 33.3 KB

    const int n0 = blockIdx.x * NT;
    const int tid = threadIdx.x;

    // ---- Phase 1: load E[n0..n0+63][:] f4-coalesced (full 512 B rows per
    //      half-wave), transpose into LDS. Same as R1.
    {
        const int c = tid & 31;   // d = 4c..4c+3
        const int r = tid >> 5;   // n row 0..7 per iter
        #pragma unroll
        for (int it = 0; it < NT / 8; ++it) {
            const int n = r + it * 8;
            const f4_t v = *reinterpret_cast<const f4_t*>(
                &E[(size_t)(n0 + n) * DD + (c << 2)]);
            lds[(c << 2) + 0][n] = v.x;
            lds[(c << 2) + 1][n] = v.y;
            lds[(c << 2) + 2][n] = v.z;
            lds[(c << 2) + 3][n] = v.w;
        }
    }
    __syncthreads();

    // ---- Phase 2: write out[b][d][n0..n0+63] for ALL b, all d.
    //      Identical instruction shape to R1 (wave = 4 rows x 16 f4,
    //      d fastest), just 8x more iterations per block.
    const int j = tid & 15;        // f4 slot within row (n_local = 4j)
    const int row0 = tid >> 4;     // 0..15
    #pragma unroll 8
    for (int it = 0; it < (NB * DD) / 16; ++it) {   // 256 iters
        const int row = row0 + it * 16;             // 0..4095
        const int d = row & (DD - 1);
        const int b = row >> 7;
        f4_t v;
        v.x = lds[d][(j << 2) + 0];
        v.y = lds[d][(j << 2) + 1];
        v.z = lds[d][(j << 2) + 2];
        v.w = lds[d][(j << 2) + 3];
        const size_t oidx = (((size_t)b * DD + d) * NN) + n0 + (j << 2);
        *reinterpret_cast<f4_t*>(&out[oidx]) = v;
    }
}

extern "C" void kernel_launch(void* const* d_in, const int* in_sizes, int n_in,
                              void* d_out, int out_size, void* d_ws, size_t ws_size,
                              hipStream_t stream) {
    const float* E = (const float*)d_in[0];  // [16384,128]
    float* out = (float*)d_out;              // [32,128,16384,1]
    hipLaunchKernelGGL(tree_embed_kernel, dim3(NN / NT), dim3(256), 0, stream,
                       E, out);
}

// Round 7
// 45.943 us; speedup vs baseline: 1.2313x; 1.0046x over previous
//
#include <hip/hip_runtime.h>
#include <hip/hip_bf16.h>

// out[b][d][n] = E[n][d], b<32, d<128, n<16384.
// R6 structure (grid=256 long-lived blocks, single E read, d-fastest store
// order) but tile = 32d x 256n: each wave-store instruction is ONE fully
// contiguous 1 KB run within a (b,d) row (vs R6's 4x256B scatter), and the
// LDS read collapses to a single conflict-free ds_read_b128 per iter.
// Isolates the store-segment-length variable. Floor ~= 42-43 us honest.

#define NN 16384
#define DD 128
#define NB 32
#define DT 32    // d per block
#define NT 256   // n per block

typedef float f4_t __attribute__((ext_vector_type(4)));

__global__ __launch_bounds__(256) void tree_embed_kernel(
    const float* __restrict__ E, float* __restrict__ out) {
    // +4 pad: row stride 260 floats = 1040 B, keeps every row 16B-aligned
    // for ds_read_b128 (bank-conflict-free: wave reads 1 KB contiguous).
    __shared__ float lds[DT][NT + 4];  // 33.3 KB

    const int d0 = blockIdx.x * DT;
    const int n0 = blockIdx.y * NT;
    const int tid = threadIdx.x;

    // ---- Phase 1: load E[n0:n0+256][d0:d0+32] (128 B per row-slice,
    //      8 lanes per row), transpose into LDS.
    {
        const int c = tid & 7;      // f4 within 32-d slice: d_local = 4c..4c+3
        const int r0 = tid >> 3;    // 0..31 rows per iter
        #pragma unroll
        for (int i = 0; i < NT / 32; ++i) {  // 8 iters
            const int n = r0 + (i << 5);
            const f4_t v = *reinterpret_cast<const f4_t*>(
                &E[(size_t)(n0 + n) * DD + d0 + (c << 2)]);
            lds[(c << 2) + 0][n] = v.x;
            lds[(c << 2) + 1][n] = v.y;
            lds[(c << 2) + 2][n] = v.z;
            lds[(c << 2) + 3][n] = v.w;
        }
    }
    __syncthreads();

    // ---- Phase 2: 1024 (b,d) rows of 1 KB each. Wave w takes row
    //      r = w + 4*it (d fastest, stride-4; 4 waves cover 4 adjacent d).
    //      One ds_read_b128 + one 1KB-contiguous wave store per iter.
    const int j = tid & 63;     // f4 slot: n_local = 4j, covers full 1 KB row
    const int w = tid >> 6;     // 0..3
    #pragma unroll 8
    for (int it = 0; it < (NB * DT) / 4; ++it) {   // 256 iters
        const int r = w + (it << 2);
        const int d = r & (DT - 1);
        const int b = r >> 5;
        const f4_t v = *reinterpret_cast<const f4_t*>(&lds[d][j << 2]);
        const size_t oidx = ((size_t)b * DD + d0 + d) * NN + n0 + (j << 2);
        *reinterpret_cast<f4_t*>(&out[oidx]) = v;
    }
}

extern "C" void kernel_launch(void* const* d_in, const int* in_sizes, int n_in,
                              void* d_out, int out_size, void* d_ws, size_t ws_size,
                              hipStream_t stream) {
    const float* E = (const float*)d_in[0];  // [16384,128]
    float* out = (float*)d_out;              // [32,128,16384,1]
    dim3 grid(DD / DT, NN / NT);             // 4 x 64 = 256 blocks
    hipLaunchKernelGGL(tree_embed_kernel, grid, dim3(256), 0, stream, E, out);
}